// Round 4
// baseline (338.794 us; speedup 1.0000x reference)
//
#include <hip/hip_runtime.h>

#define NL 64
#define SQ 512
#define BATCH 1024

typedef float v2f __attribute__((ext_vector_type(2)));

__device__ __forceinline__ float lane0_bcast(float v) {
    return __uint_as_float(__builtin_amdgcn_readfirstlane(__float_as_uint(v)));
}

// One wave per batch row; lane j owns next-label j.
// Exp-domain recurrence: p'_j = expE_j * sum_i p_i * ET[i][j].
// Broadcast of p via LDS same-address reads (all-VGPR datapath; avoids the
// v_readlane VALU->SGPR->VALU RAW hazard that stalled round 3).
// Inner product as 32 v_pk_fma_f32 (packed fp32) instead of 64 scalar FMAs.
__global__ __launch_bounds__(64, 1) void crf_fwd(
    const float* __restrict__ emissions,   // [B, S, L]
    const int*   __restrict__ mask,        // [B, S]
    const float* __restrict__ trans,       // [L, L]  (prev, next)
    const float* __restrict__ start_t,     // [L]
    const float* __restrict__ end_t,       // [L]
    float* __restrict__ out)               // [B]
{
    const int b = blockIdx.x;
    const int j = threadIdx.x;             // next-label index

    const float* em = emissions + (size_t)b * SQ * NL;
    const int*   mk = mask + (size_t)b * SQ;

    // ET column j as 32 packed pairs: et2[k] = { e^T[2k][j], e^T[2k+1][j] }
    v2f et2[NL / 2];
#pragma unroll
    for (int k = 0; k < NL / 2; ++k) {
        et2[k].x = __expf(trans[(2 * k + 0) * NL + j]);
        et2[k].y = __expf(trans[(2 * k + 1) * NL + j]);
    }

    __shared__ __align__(16) float plds[NL];   // 256 B, single wave -> no barrier

    float p, logC;
    {
        const float s0 = start_t[j] + em[j];   // t = 0
        const float C  = lane0_bcast(s0);
        p    = __expf(s0 - C);
        logC = C;
    }

    auto step = [&](float ex, int m) {
        plds[j] = p;                           // ds_write_b32 (stride-1: free 2-way)
        v2f a0 = {0.f, 0.f}, a1 = {0.f, 0.f}, a2 = {0.f, 0.f}, a3 = {0.f, 0.f};
        const float4* f4 = (const float4*)plds;
#pragma unroll
        for (int k = 0; k < 16; k += 2) {      // 16x ds_read_b128, same addr = broadcast
            const float4 fa = f4[k];
            const float4 fb = f4[k + 1];
            const v2f pa0 = {fa.x, fa.y}, pa1 = {fa.z, fa.w};
            const v2f pb0 = {fb.x, fb.y}, pb1 = {fb.z, fb.w};
            a0 = __builtin_elementwise_fma(pa0, et2[2 * k + 0], a0);
            a1 = __builtin_elementwise_fma(pa1, et2[2 * k + 1], a1);
            a2 = __builtin_elementwise_fma(pb0, et2[2 * k + 2], a2);
            a3 = __builtin_elementwise_fma(pb1, et2[2 * k + 3], a3);
        }
        const v2f s = (a0 + a1) + (a2 + a3);
        const float pn = ex * (s.x + s.y);
        p = m ? pn : p;
    };

    // software pipeline: raw emissions prefetched one 4-step group ahead
    float raw0 = em[1 * NL + j];
    float raw1 = em[2 * NL + j];
    float raw2 = em[3 * NL + j];
    float raw3 = em[4 * NL + j];

    for (int g = 0; g < 127; ++g) {
        const int t = 1 + 4 * g;               // steps t .. t+3

        const float ex0 = __expf(raw0);
        const float ex1 = __expf(raw1);
        const float ex2 = __expf(raw2);
        const float ex3 = __expf(raw3);

        const int t4 = t + 4;
        const int t7 = (t + 7 < SQ) ? (t + 7) : (SQ - 1);
        raw0 = em[t4 * NL + j];
        raw1 = em[(t4 + 1) * NL + j];
        raw2 = em[(t4 + 2) * NL + j];
        raw3 = em[t7 * NL + j];

        const int m0 = mk[t + 0];
        const int m1 = mk[t + 1];
        const int m2 = mk[t + 2];
        const int m3 = mk[t + 3];

        step(ex0, m0);
        step(ex1, m1);
        step(ex2, m2);
        step(ex3, m3);

        // renorm every 4 steps: p stays in fp32 range; score_j = logC + log(p_j)
        const float r0 = lane0_bcast(p);
        const float rs = __builtin_amdgcn_rcpf(r0);
        logC += __logf(r0);
        p *= rs;
    }

    // tail: t = 509, 510, 511
    {
        const float ex0 = __expf(raw0);
        const float ex1 = __expf(raw1);
        const float ex2 = __expf(raw2);
        const int   m0  = mk[509];
        const int   m1  = mk[510];
        const int   m2  = mk[511];
        step(ex0, m0);
        step(ex1, m1);
        step(ex2, m2);
    }

    // out[b] = logC + log( sum_j p_j * exp(end_t[j]) )
    float v = p * __expf(end_t[j]);
#pragma unroll
    for (int off = 32; off; off >>= 1) v += __shfl_xor(v, off);
    if (j == 0) out[b] = logC + __logf(v);
}

extern "C" void kernel_launch(void* const* d_in, const int* in_sizes, int n_in,
                              void* d_out, int out_size, void* d_ws, size_t ws_size,
                              hipStream_t stream) {
    const float* emissions = (const float*)d_in[0];
    const int*   mask      = (const int*)d_in[1];
    const float* trans     = (const float*)d_in[2];
    const float* start_t   = (const float*)d_in[3];
    const float* end_t     = (const float*)d_in[4];
    float* out = (float*)d_out;

    crf_fwd<<<BATCH, NL, 0, stream>>>(emissions, mask, trans, start_t, end_t, out);
}